// Round 7
// baseline (247.597 us; speedup 1.0000x reference)
//
#include <hip/hip_runtime.h>

#define SEQ   2048
#define EMBD  1024
#define HEADS 16
#define HDIM  64
#define MTOT  8192
#define LOG2E 1.44269504f

typedef __attribute__((ext_vector_type(8))) _Float16 half8;
typedef __attribute__((ext_vector_type(4))) _Float16 half4;
typedef __attribute__((ext_vector_type(2))) __fp16 fp16x2;
typedef __attribute__((ext_vector_type(4))) float f32x4;
typedef __attribute__((ext_vector_type(16))) float f32x16;

__device__ __forceinline__ f32x4 mfma16(half8 a, half8 b, f32x4 c) {
  return __builtin_amdgcn_mfma_f32_16x16x32_f16(a, b, c, 0, 0, 0);
}
__device__ __forceinline__ f32x16 mfma32(half8 a, half8 b, f32x16 c) {
  return __builtin_amdgcn_mfma_f32_32x32x16_f16(a, b, c, 0, 0, 0);
}

__device__ __forceinline__ void gload_lds16(const void* g, void* l) {
  __builtin_amdgcn_global_load_lds(
      (const __attribute__((address_space(1))) unsigned int*)g,
      (__attribute__((address_space(3))) unsigned int*)l, 16, 0, 0);
}

__device__ __forceinline__ unsigned pk2(float a, float b) {
  union { fp16x2 v; unsigned u; } t;
  t.v = __builtin_amdgcn_cvt_pkrtz(a, b);
  return t.u;
}

// ---------------- cast fp32 -> fp16, 8 elems/thread ----------------
__global__ void k_cvt(const float* __restrict__ in, _Float16* __restrict__ out) {
  size_t i = (size_t)blockIdx.x * blockDim.x + threadIdx.x;
  const f32x4* in4 = (const f32x4*)in;
  f32x4 a = in4[2 * i], b = in4[2 * i + 1];
  half8 h;
  h[0] = (_Float16)a[0]; h[1] = (_Float16)a[1];
  h[2] = (_Float16)a[2]; h[3] = (_Float16)a[3];
  h[4] = (_Float16)b[0]; h[5] = (_Float16)b[1];
  h[6] = (_Float16)b[2]; h[7] = (_Float16)b[3];
  *(half8*)(out + i * 8) = h;
}

// ------- LDS-tiled transpose fp32 [R][C] -> fp16 [C][R], 64x64 tiles -------
__global__ __launch_bounds__(256) void k_transpose(const float* __restrict__ in,
                                                   _Float16* __restrict__ out,
                                                   int R, int C) {
  __shared__ _Float16 tile[64][65];
  const int tid = threadIdx.x;
  const int r0 = blockIdx.y * 64, c0 = blockIdx.x * 64;
  const int tr = tid >> 6;   // 0..3
  const int tc = tid & 63;
  #pragma unroll
  for (int i = 0; i < 16; ++i) {
    const int r = i * 4 + tr;
    tile[r][tc] = (_Float16)in[(size_t)(r0 + r) * C + c0 + tc];
  }
  __syncthreads();
  #pragma unroll
  for (int i = 0; i < 16; ++i) {
    const int cc = i * 4 + tr;            // column of in = row of out
    out[(size_t)(c0 + cc) * R + r0 + tc] = tile[tc][cc];  // coalesced in tc
  }
}

// ------- GEMM: C[M,N] = A[M,1024] @ Bt[N,1024]^T + bias -------
template<int EPI>
__global__ __launch_bounds__(256) void k_gemm(
    const _Float16* __restrict__ A, const _Float16* __restrict__ Bt,
    const float* __restrict__ bias, float* __restrict__ outf,
    _Float16* __restrict__ q, _Float16* __restrict__ k, _Float16* __restrict__ vt)
{
  __shared__ _Float16 sm[2 * 128 * 64];
  _Float16* sA = sm;
  _Float16* sB = sm + 128 * 64;
  const int tid = threadIdx.x;
  const int l = tid & 63, g = l >> 4, c = l & 15;
  const int w = tid >> 6;
  const int wm = (w >> 1) * 64, wn = (w & 1) * 64;
  const int rowBase = blockIdx.y * 128;
  const int colBase = blockIdx.x * 128;

  f32x4 acc[4][4] = {};

  const _Float16* Ag = A + (size_t)(rowBase + (tid >> 3)) * 1024 + (tid & 7) * 8;
  const _Float16* Bg = Bt + (size_t)(colBase + (tid >> 3)) * 1024 + (tid & 7) * 8;
  _Float16* la = sA + tid * 8;
  _Float16* lb = sB + tid * 8;

  for (int kt = 0; kt < 16; ++kt) {
    const _Float16* ag = Ag + kt * 64;
    const _Float16* bg = Bg + kt * 64;
    #pragma unroll
    for (int i = 0; i < 4; ++i) {
      gload_lds16(ag + (size_t)i * 32 * 1024, la + i * 256 * 8);
      gload_lds16(bg + (size_t)i * 32 * 1024, lb + i * 256 * 8);
    }
    __syncthreads();
    #pragma unroll
    for (int kk = 0; kk < 2; ++kk) {
      half8 af[4], bf[4];
      #pragma unroll
      for (int t = 0; t < 4; ++t)
        af[t] = *(const half8*)(sA + (wm + t * 16 + c) * 64 + kk * 32 + g * 8);
      #pragma unroll
      for (int t = 0; t < 4; ++t)
        bf[t] = *(const half8*)(sB + (wn + t * 16 + c) * 64 + kk * 32 + g * 8);
      #pragma unroll
      for (int mt = 0; mt < 4; ++mt)
        #pragma unroll
        for (int nt = 0; nt < 4; ++nt)
          acc[mt][nt] = mfma16(af[mt], bf[nt], acc[mt][nt]);
    }
    __syncthreads();
  }

  #pragma unroll
  for (int mt = 0; mt < 4; ++mt) {
    #pragma unroll
    for (int nt = 0; nt < 4; ++nt) {
      const int col = colBase + wn + nt * 16 + c;
      const float bv = bias[col];
      #pragma unroll
      for (int r = 0; r < 4; ++r) {
        const int row = rowBase + wm + mt * 16 + g * 4 + r;
        const float val = acc[mt][nt][r] + bv;
        if constexpr (EPI == 0) {
          const int s = col >> 10, h = (col >> 6) & 15, d = col & 63;
          const int b = row >> 11, n = row & 2047;
          const int bh = b * HEADS + h;
          const _Float16 hv = (_Float16)val;
          if (s == 2)      vt[((size_t)bh * HDIM + d) * SEQ + n] = hv;
          else if (s == 1) k [((size_t)bh * SEQ + n) * HDIM + d] = hv;
          else             q [((size_t)bh * SEQ + n) * HDIM + d] = hv;
        } else {
          outf[(size_t)row * EMBD + col] = val;
        }
      }
    }
  }
}

// ---------------- flash attention fwd (32x32 MFMA, per-lane softmax) -------
// 8 waves x 32 q-rows = 256 q/block; KVBLK=64. S^T = mfma32(K, Q): q = lane&31
// -> m/l/cor/O-rescale fully per-lane (pair-uniform via wave-uniform skip).
// P goes through PER-WAVE LDS so PV's A (V^T) and B (P^T) are read with the
// SAME k-permutation -> correct for any true MFMA input layout (invariance).
__global__ __launch_bounds__(512, 4) void k_attn(
    const _Float16* __restrict__ q, const _Float16* __restrict__ kg,
    const _Float16* __restrict__ vt, _Float16* __restrict__ aout)
{
  // Ks[64][72] + Vs[64][72] + per-wave Pw[32][76] x 8  = 57344 B
  __shared__ _Float16 sm[64 * 72 * 2 + 8 * 32 * 76];
  _Float16* Ks = sm;
  _Float16* Vs = sm + 64 * 72;
  const int tid = threadIdx.x;
  const int w = tid >> 6, l = tid & 63;
  const int q32 = l & 31, hi = l >> 5;
  _Float16* Pw = sm + 2 * 64 * 72 + w * 32 * 76;   // per-wave P[q 0..31][76]

  // XCD-chunked bijective swizzle (512 blocks, 8 XCDs -> 64 contiguous each)
  const int orig = blockIdx.x;
  const int lb = (orig & 7) * 64 + (orig >> 3);
  const int bh = lb >> 3;                  // 8 q-tiles per bh
  const int n0 = (lb & 7) * 256 + w * 32;

  const _Float16* qb = q  + (size_t)bh * SEQ * HDIM;
  const _Float16* kb = kg + (size_t)bh * SEQ * HDIM;
  const _Float16* vb = vt + (size_t)bh * HDIM * SEQ;
  const int row0 = tid >> 3, cb = tid & 7;

  // Q fragments (B operand): lane holds q = q32, d = ch*16 + hi*8 .. +7
  half8 aq[4];
  #pragma unroll
  for (int ch = 0; ch < 4; ++ch) {
    half8 t = *(const half8*)(qb + (size_t)(n0 + q32) * HDIM + ch * 16 + hi * 8);
    aq[ch] = t * (_Float16)0.125f;
  }

  float m_ = -1e30f, l_ = 0.f;             // m_ pair-uniform; l_ per-lane partial
  f32x16 o0 = {}, o1 = {};                 // O^T: col q = lane&31

  // T14 prologue: tile 0 into registers
  half8 kr = *(const half8*)(kb + (size_t)tid * 8);
  half8 vr = *(const half8*)(vb + (size_t)row0 * SEQ + cb * 8);

  for (int kt = 0; kt < SEQ / 64; ++kt) {
    __syncthreads();
    *(half8*)(Ks + row0 * 72 + cb * 8) = kr;
    *(half8*)(Vs + row0 * 72 + cb * 8) = vr;
    if (kt + 1 < SEQ / 64) {
      kr = *(const half8*)(kb + (size_t)(kt + 1) * 64 * HDIM + (size_t)tid * 8);
      vr = *(const half8*)(vb + (size_t)row0 * SEQ + (kt + 1) * 64 + cb * 8);
    }
    __syncthreads();

    // S^T[key][q]: s0 = keys 0..31, s1 = keys 32..63 (per lane: 16 each)
    // C-layout: key-in-32 = (r&3) + 8*(r>>2) + 4*hi, col q = lane&31
    f32x16 s0 = {}, s1 = {};
    __builtin_amdgcn_s_setprio(1);
    #pragma unroll
    for (int ch = 0; ch < 4; ++ch) {
      half8 ak0 = *(const half8*)(Ks + q32 * 72 + ch * 16 + hi * 8);
      half8 ak1 = *(const half8*)(Ks + (32 + q32) * 72 + ch * 16 + hi * 8);
      s0 = mfma32(ak0, aq[ch], s0);
      s1 = mfma32(ak1, aq[ch], s1);
    }
    __builtin_amdgcn_s_setprio(0);

    // local max over this lane's 32 scores
    float mx = fmaxf(s0[0], s1[0]);
    #pragma unroll
    for (int e = 1; e < 16; ++e) mx = fmaxf(mx, fmaxf(s0[e], s1[e]));

    if (__any(mx > m_ + 8.0f)) {           // slow path (wave-uniform decision)
      const float fm = fmaxf(mx, __shfl_xor(mx, 32, 64));  // pair-combined max
      const float mo = m_;
      const float mn = fmaxf(mo, fm);
      const float cor = __builtin_amdgcn_exp2f((mo - mn) * LOG2E);
      m_ = mn;
      l_ *= cor;
      #pragma unroll
      for (int e = 0; e < 16; ++e) { o0[e] *= cor; o1[e] *= cor; }
    }

    // exp in place + per-lane partial sum; write P to per-wave LDS.
    // s regs 4j..4j+3 = keys 8j+4hi .. +3 (contiguous 4) -> ds_write_b64
    float rs = 0.f;
    #pragma unroll
    for (int e = 0; e < 16; ++e) {
      s0[e] = __builtin_amdgcn_exp2f((s0[e] - m_) * LOG2E);
      s1[e] = __builtin_amdgcn_exp2f((s1[e] - m_) * LOG2E);
      rs += s0[e] + s1[e];
    }
    l_ += rs;

    _Float16* prow = Pw + q32 * 76;
    #pragma unroll
    for (int j = 0; j < 4; ++j) {
      union { unsigned u[2]; half4 h; } t0, t1;
      t0.u[0] = pk2(s0[4 * j], s0[4 * j + 1]);
      t0.u[1] = pk2(s0[4 * j + 2], s0[4 * j + 3]);
      t1.u[0] = pk2(s1[4 * j], s1[4 * j + 1]);
      t1.u[1] = pk2(s1[4 * j + 2], s1[4 * j + 3]);
      *(half4*)(prow + 8 * j + 4 * hi) = t0.h;        // keys 8j+4hi..+3
      *(half4*)(prow + 32 + 8 * j + 4 * hi) = t1.h;   // keys 32+8j+4hi..+3
    }

    // PV: O^T[d][q] += V^T[d][k] * P^T[k][q]; A and B read with SAME sigma.
    __builtin_amdgcn_s_setprio(1);
    #pragma unroll
    for (int ch = 0; ch < 4; ++ch) {
      half8 pf  = *(const half8*)(Pw + q32 * 76 + ch * 16 + hi * 8);
      half8 av0 = *(const half8*)(Vs + q32 * 72 + ch * 16 + hi * 8);
      half8 av1 = *(const half8*)(Vs + (32 + q32) * 72 + ch * 16 + hi * 8);
      o0 = mfma32(av0, pf, o0);
      o1 = mfma32(av1, pf, o1);
    }
    __builtin_amdgcn_s_setprio(0);
  }

  // epilogue: per-lane 1/l; transpose O through PRIVATE Pw (no barrier)
  float lt = l_ + __shfl_xor(l_, 32, 64);
  const float rl = __builtin_amdgcn_rcpf(lt);

  _Float16* Ot = Pw;                        // per-wave [32 q][76]
  #pragma unroll
  for (int dh = 0; dh < 2; ++dh) {
    #pragma unroll
    for (int j = 0; j < 4; ++j) {
      union { unsigned u[2]; half4 h; } t;
      if (dh == 0) {
        t.u[0] = pk2(o0[4 * j] * rl, o0[4 * j + 1] * rl);
        t.u[1] = pk2(o0[4 * j + 2] * rl, o0[4 * j + 3] * rl);
      } else {
        t.u[0] = pk2(o1[4 * j] * rl, o1[4 * j + 1] * rl);
        t.u[1] = pk2(o1[4 * j + 2] * rl, o1[4 * j + 3] * rl);
      }
      // O^T regs 4j..4j+3 = d = dh*32 + 8j + 4hi .. +3
      *(half4*)(Ot + q32 * 76 + dh * 32 + 8 * j + 4 * hi) = t.h;
    }
  }

  const int b = bh >> 4, h = bh & 15;
  #pragma unroll
  for (int i = 0; i < 4; ++i) {
    const int qq = 8 * i + (l >> 3);
    half8 v = *(const half8*)(Ot + qq * 76 + (l & 7) * 8);
    *(half8*)(aout + (size_t)(b * SEQ + n0 + qq) * EMBD + h * HDIM + (l & 7) * 8) = v;
  }
}

extern "C" void kernel_launch(void* const* d_in, const int* in_sizes, int n_in,
                              void* d_out, int out_size, void* d_ws, size_t ws_size,
                              hipStream_t stream) {
  const float* x    = (const float*)d_in[0];
  const float* Wqkv = (const float*)d_in[1];
  const float* bqkv = (const float*)d_in[2];
  const float* Wout = (const float*)d_in[3];
  const float* bout = (const float*)d_in[4];
  float* out = (float*)d_out;

  // workspace layout (halves). aout reuses xh (dead after QKV GEMM).
  _Float16* ws    = (_Float16*)d_ws;
  _Float16* xh    = ws;                                   // 8M
  _Float16* wqkvt = xh + (size_t)MTOT * EMBD;             // 3M
  _Float16* woutt = wqkvt + (size_t)3 * EMBD * EMBD;      // 1M
  _Float16* qbuf  = woutt + (size_t)EMBD * EMBD;          // 8M
  _Float16* kbuf  = qbuf + (size_t)MTOT * EMBD;           // 8M
  _Float16* vtbuf = kbuf + (size_t)MTOT * EMBD;           // 8M
  _Float16* aout  = xh;

  k_cvt<<<4096, 256, 0, stream>>>(x, xh);
  k_transpose<<<dim3(48, 16), 256, 0, stream>>>(Wqkv, wqkvt, 1024, 3072);
  k_transpose<<<dim3(16, 16), 256, 0, stream>>>(Wout, woutt, 1024, 1024);
  k_gemm<0><<<dim3(24, 64), 256, 0, stream>>>(xh, wqkvt, bqkv, nullptr,
                                              qbuf, kbuf, vtbuf);
  k_attn<<<512, 512, 0, stream>>>(qbuf, kbuf, vtbuf, aout);
  k_gemm<1><<<dim3(8, 64), 256, 0, stream>>>(aout, woutt, bout, out,
                                             nullptr, nullptr, nullptr);
}